// Round 2
// baseline (586.926 us; speedup 1.0000x reference)
//
#include <hip/hip_runtime.h>
#include <hip/hip_bf16.h>

#define BATCH 1024
#define DIM 512
#define NCLS 100000
#define SCALE 30.0f
#define MARGIN 0.4f
#define BM 128
#define BN 64
#define BK 64
#define NT ((NCLS + BN - 1) / BN)   /* 1563 col tiles */

typedef __bf16 bf16x8 __attribute__((ext_vector_type(8)));
typedef __bf16 bf16x4 __attribute__((ext_vector_type(4)));
typedef float f32x4 __attribute__((ext_vector_type(4)));

// ---------------- kernel 1: row-normalize x, emit bf16 ----------------
__global__ __launch_bounds__(256) void k_norm(const float* __restrict__ x,
                                              __bf16* __restrict__ xb) {
    int row  = blockIdx.x * 4 + (threadIdx.x >> 6);
    int lane = threadIdx.x & 63;
    const float* xr = x + (size_t)row * DIM;
    float4 v0 = *reinterpret_cast<const float4*>(xr + lane * 4);
    float4 v1 = *reinterpret_cast<const float4*>(xr + 256 + lane * 4);
    float ss = v0.x*v0.x + v0.y*v0.y + v0.z*v0.z + v0.w*v0.w
             + v1.x*v1.x + v1.y*v1.y + v1.z*v1.z + v1.w*v1.w;
#pragma unroll
    for (int m = 1; m < 64; m <<= 1) ss += __shfl_xor(ss, m);
    float inv = 1.0f / fmaxf(sqrtf(ss), 1e-12f);
    bf16x4 o0 = { (__bf16)(v0.x*inv), (__bf16)(v0.y*inv), (__bf16)(v0.z*inv), (__bf16)(v0.w*inv) };
    bf16x4 o1 = { (__bf16)(v1.x*inv), (__bf16)(v1.y*inv), (__bf16)(v1.z*inv), (__bf16)(v1.w*inv) };
    *reinterpret_cast<bf16x4*>(xb + (size_t)row * DIM + lane * 4)       = o0;
    *reinterpret_cast<bf16x4*>(xb + (size_t)row * DIM + 256 + lane * 4) = o1;
}

// ------- kernel 2: fused GEMM (bf16 MFMA) + masked exp row-partials -------
// grid: NT*8 blocks; bid = ct*8 + rt (consecutive blocks share the W tile)
__global__ __launch_bounds__(256) void k_main(const __bf16* __restrict__ xb,
                                              const float* __restrict__ W,
                                              const int* __restrict__ lab32,
                                              float* __restrict__ part,
                                              float* __restrict__ tgt) {
    int bid = blockIdx.x;
    int ct  = bid >> 3;
    int rt  = bid & 7;
    int tid = threadIdx.x;
    int wid = tid >> 6;
    int lane = tid & 63;
    int rowBase = rt * BM;
    int colBase = ct * BN;

    __shared__ __bf16 Asm[BM * BK];
    __shared__ __bf16 Bsm[BN * BK];
    __shared__ int    slab[BM];
    __shared__ int    sflag;

    // detect int64 vs int32 label layout (hi words all zero => int64)
    if (tid < 64) {
        int o = 0;
        for (int i = lane; i < 512; i += 64) o |= lab32[2 * i + 1];
#pragma unroll
        for (int m = 1; m < 64; m <<= 1) o |= __shfl_xor(o, m);
        if (lane == 0) sflag = o;
    }
    __syncthreads();
    bool is64 = (sflag == 0);
    if (tid < BM) slab[tid] = is64 ? lab32[2 * (rowBase + tid)] : lab32[rowBase + tid];

    f32x4 acc[2][4];
#pragma unroll
    for (int m = 0; m < 2; m++)
#pragma unroll
        for (int n = 0; n < 4; n++) acc[m][n] = (f32x4){0.f, 0.f, 0.f, 0.f};

    for (int k0 = 0; k0 < DIM; k0 += BK) {
        __syncthreads();
        // stage A: 128x64 bf16, XOR-swizzled
#pragma unroll
        for (int i = 0; i < 4; i++) {
            int idx = i * 2048 + tid * 8;
            int r = idx >> 6, k = idx & 63;
            bf16x8 v = *reinterpret_cast<const bf16x8*>(xb + (size_t)(rowBase + r) * DIM + k0 + k);
            int byte = (r * 128 + k * 2) ^ ((r & 7) << 4);
            *reinterpret_cast<bf16x8*>(reinterpret_cast<char*>(Asm) + byte) = v;
        }
        // stage B: 64x64 fp32 -> bf16, XOR-swizzled (zero-pad class tail)
#pragma unroll
        for (int i = 0; i < 4; i++) {
            int idx = i * 1024 + tid * 4;
            int r = idx >> 6, k = idx & 63;
            int c = colBase + r;
            float4 v = (c < NCLS) ? *reinterpret_cast<const float4*>(W + (size_t)c * DIM + k0 + k)
                                  : make_float4(0.f, 0.f, 0.f, 0.f);
            bf16x4 h = { (__bf16)v.x, (__bf16)v.y, (__bf16)v.z, (__bf16)v.w };
            int byte = (r * 128 + k * 2) ^ ((r & 7) << 4);
            *reinterpret_cast<bf16x4*>(reinterpret_cast<char*>(Bsm) + byte) = h;
        }
        __syncthreads();
        // compute: wave w -> rows w*32..w*32+31, all 64 cols
#pragma unroll
        for (int ks = 0; ks < 2; ks++) {
            bf16x8 a[2], b[4];
            int kk = (ks * 32 + (lane >> 4) * 8) * 2;   // byte offset in k
#pragma unroll
            for (int m = 0; m < 2; m++) {
                int r = wid * 32 + m * 16 + (lane & 15);
                int byte = (r * 128 + kk) ^ ((r & 7) << 4);
                a[m] = *reinterpret_cast<const bf16x8*>(reinterpret_cast<const char*>(Asm) + byte);
            }
#pragma unroll
            for (int n = 0; n < 4; n++) {
                int r = n * 16 + (lane & 15);
                int byte = (r * 128 + kk) ^ ((r & 7) << 4);
                b[n] = *reinterpret_cast<const bf16x8*>(reinterpret_cast<const char*>(Bsm) + byte);
            }
#pragma unroll
            for (int m = 0; m < 2; m++)
#pragma unroll
                for (int n = 0; n < 4; n++)
                    acc[m][n] = __builtin_amdgcn_mfma_f32_16x16x32_bf16(a[m], b[n], acc[m][n], 0, 0, 0);
        }
    }

    // epilogue: target logit + masked exp row-sums (wave-local rows)
#pragma unroll
    for (int m = 0; m < 2; m++) {
#pragma unroll
        for (int r = 0; r < 4; r++) {
            int trow = wid * 32 + m * 16 + (lane >> 4) * 4 + r;
            int grow = rowBase + trow;
            int lb = slab[trow];
            float s = 0.f;
#pragma unroll
            for (int n = 0; n < 4; n++) {
                int gcol = colBase + n * 16 + (lane & 15);
                float v = acc[m][n][r];
                if (gcol == lb) tgt[grow] = v;
                if (gcol < NCLS && gcol != lb) s += __expf(SCALE * v);
            }
#pragma unroll
            for (int mm = 1; mm < 16; mm <<= 1) s += __shfl_xor(s, mm);
            if ((lane & 15) == 0) part[(size_t)grow * NT + ct] = s;
        }
    }
}

// ---------------- kernel 3: per-row reduce + loss term ----------------
__global__ __launch_bounds__(256) void k_row(const float* __restrict__ part,
                                             const float* __restrict__ tgt,
                                             float* __restrict__ Lrow) {
    int row = blockIdx.x;
    int tid = threadIdx.x;
    float s = 0.f;
    for (int t = tid; t < NT; t += 256) s += part[(size_t)row * NT + t];
#pragma unroll
    for (int m = 1; m < 64; m <<= 1) s += __shfl_xor(s, m);
    __shared__ float red[4];
    if ((tid & 63) == 0) red[tid >> 6] = s;
    __syncthreads();
    if (tid == 0) {
        float excl = red[0] + red[1] + red[2] + red[3];
        float num = SCALE * (tgt[row] - MARGIN);
        float den = __expf(num) + excl;
        Lrow[row] = num - logf(den);
    }
}

// ---------------- kernel 4: mean ----------------
__global__ __launch_bounds__(1024) void k_final(const float* __restrict__ Lrow,
                                                float* __restrict__ out) {
    int tid = threadIdx.x;
    float v = Lrow[tid];
#pragma unroll
    for (int m = 1; m < 64; m <<= 1) v += __shfl_xor(v, m);
    __shared__ float red[16];
    if ((tid & 63) == 0) red[tid >> 6] = v;
    __syncthreads();
    if (tid == 0) {
        float s = 0.f;
#pragma unroll
        for (int i = 0; i < 16; i++) s += red[i];
        out[0] = -s / (float)BATCH;
    }
}

extern "C" void kernel_launch(void* const* d_in, const int* in_sizes, int n_in,
                              void* d_out, int out_size, void* d_ws, size_t ws_size,
                              hipStream_t stream) {
    const float* x   = (const float*)d_in[0];
    const int*   lab = (const int*)d_in[1];
    const float* W   = (const float*)d_in[2];
    float* out = (float*)d_out;

    char* ws = (char*)d_ws;
    __bf16* xb  = (__bf16*)ws;                                   // 1 MiB
    float*  part = (float*)(ws + (1 << 20));                     // 1024*NT*4 = 6.4 MB
    float*  tgt  = (float*)(ws + (1 << 20) + (size_t)BATCH * NT * 4);
    float*  Lrow = tgt + BATCH;

    k_norm <<<BATCH / 4, 256, 0, stream>>>(x, xb);
    k_main <<<NT * 8,    256, 0, stream>>>(xb, W, lab, part, tgt);
    k_row  <<<BATCH,     256, 0, stream>>>(part, tgt, Lrow);
    k_final<<<1,        1024, 0, stream>>>(Lrow, out);
}